// Round 6
// baseline (278.602 us; speedup 1.0000x reference)
//
#include <hip/hip_runtime.h>
#include <math.h>

#define NN 10000
#define NE 160000
#define IN_DIM 256
#define HID_DIM 512
#define OUT_DIM 256

typedef unsigned short u16;
typedef __attribute__((ext_vector_type(8))) short bf16x8;
typedef __attribute__((ext_vector_type(4))) float f32x4;

// ---------------- bf16 split helpers ----------------

static __device__ __forceinline__ u16 f2bf(float f) {
    union { float f; unsigned u; } v; v.f = f;
    unsigned r = v.u + 0x7fffu + ((v.u >> 16) & 1u);  // RNE
    return (u16)(r >> 16);
}
static __device__ __forceinline__ float bf2f(u16 h) {
    union { unsigned u; float f; } v; v.u = ((unsigned)h) << 16;
    return v.f;
}

// ---------------- degree / CSR build (self-loops included) ----------------

__global__ void k_zero_deg(int* __restrict__ deg) {
    int i = blockIdx.x * blockDim.x + threadIdx.x;
    if (i < NN) deg[i] = 0;
}

__global__ void k_count_deg(const int* __restrict__ dst, int* __restrict__ deg) {
    int e = blockIdx.x * blockDim.x + threadIdx.x;
    if (e < NE) atomicAdd(&deg[dst[e]], 1);
}

__launch_bounds__(1024)
__global__ void k_scan(const int* __restrict__ deg, int* __restrict__ row,
                       int* __restrict__ csr, float* __restrict__ dinv) {
    __shared__ int sdeg[10240];
    __shared__ int sums[1024];
    const int tid = threadIdx.x;
    for (int i = tid; i < NN; i += 1024) sdeg[i] = deg[i];
    __syncthreads();
    const int CH = 10;
    int base = tid * CH;
    int s = 0;
    for (int j = 0; j < CH; ++j) {
        int i = base + j;
        if (i < NN) s += sdeg[i] + 1;
    }
    sums[tid] = s;
    __syncthreads();
    for (int off = 1; off < 1024; off <<= 1) {
        int t = (tid >= off) ? sums[tid - off] : 0;
        __syncthreads();
        sums[tid] += t;
        __syncthreads();
    }
    int run = sums[tid] - s;
    for (int j = 0; j < CH; ++j) {
        int i = base + j;
        if (i < NN) {
            int dg = sdeg[i];
            csr[run] = i;
            row[i] = run + 1;
            dinv[i] = rsqrtf((float)dg + 1.0f);
            run += dg + 1;
        }
    }
}

__global__ void k_fill(const int* __restrict__ src, const int* __restrict__ dst,
                       int* __restrict__ row, int* __restrict__ csr) {
    int e = blockIdx.x * blockDim.x + threadIdx.x;
    if (e < NE) {
        int pos = atomicAdd(&row[dst[e]], 1);
        csr[pos] = src[e];
    }
}

// ---------------- fused weight transpose + bf16 hi/lo split ----------------

__global__ void k_wsplit_all(const float* __restrict__ W1, const float* __restrict__ W2,
                             const float* __restrict__ W3,
                             u16* __restrict__ W1h, u16* __restrict__ W1l,
                             u16* __restrict__ W2h, u16* __restrict__ W2l,
                             u16* __restrict__ W3h, u16* __restrict__ W3l) {
    int idx = blockIdx.x * blockDim.x + threadIdx.x;
    const int S1 = IN_DIM * HID_DIM;
    const int S2 = HID_DIM * HID_DIM;
    const int S3 = HID_DIM * OUT_DIM;
    const float* W; u16 *Th, *Tl; int K, N, local;
    if (idx < S1)           { W = W1; Th = W1h; Tl = W1l; K = IN_DIM;  N = HID_DIM; local = idx; }
    else if (idx < S1 + S2) { W = W2; Th = W2h; Tl = W2l; K = HID_DIM; N = HID_DIM; local = idx - S1; }
    else if (idx < S1 + S2 + S3) { W = W3; Th = W3h; Tl = W3l; K = HID_DIM; N = OUT_DIM; local = idx - S1 - S2; }
    else return;
    int k = local / N, n = local - k * N;
    float v = W[local];
    u16 h = f2bf(v);
    Th[(size_t)n * K + k] = h;
    Tl[(size_t)n * K + k] = f2bf(v - bf2f(h));
}

// ---------------- bf16x3 split MFMA GEMM (XCD-pinned m-slices) ----------------
// C[M,N] = A[M,K] @ B[K,N]; A hi/lo bf16 [M][K]; B hi/lo bf16 transposed [N][K].
// Tile BM=128, BN=64, BK=32; 256 threads = 4 waves.
// Grid is 1D: id%8 = XCD slot; m-tile = (q%MT8)*8 + id%8 so ALL n-blocks of an
// m-tile land on one XCD -> A tile pair stays L2-resident (per-XCD slice 2.6MB).
// LDS in fragment-order 16B chunks: chunk(row,q) = (row>>4)*64 + q*16 + (row&15)
// -> staging writes AND fragment reads are chunk = base + lane (conflict-free).

template<bool HAS_BIAS, bool DO_TANH, bool PAIR_OUT, bool ROWSCALE>
__launch_bounds__(256)
__global__ void k_gemm_bf16x3(const u16* __restrict__ Ahi, const u16* __restrict__ Alo,
                              const u16* __restrict__ Bhi, const u16* __restrict__ Blo,
                              const float* __restrict__ bias, const float* __restrict__ rowscale,
                              float* __restrict__ C, u16* __restrict__ Chi, u16* __restrict__ Clo,
                              int M, int N, int K, int MT, int MT8) {
    __shared__ uint4 AsH[512];  // 128 rows x 4 k-chunks
    __shared__ uint4 AsL[512];
    __shared__ uint4 BsH[256];  // 64 rows x 4 k-chunks
    __shared__ uint4 BsL[256];

    const int id = blockIdx.x;
    const int xcd = id & 7;
    const int q2 = id >> 3;
    const int mt = (q2 % MT8) * 8 + xcd;
    const int nt = q2 / MT8;
    if (mt >= MT) return;

    const int tid  = threadIdx.x;
    const int wave = tid >> 6;
    const int lane = tid & 63;
    const int lr   = lane & 15;
    const int quad = lane >> 4;
    const int m_base = mt * 128;
    const int n_base = nt * 64;

    f32x4 acc[2][4] = {};

    // staging decode for chunk c: row = (c>>6)*16 + (c&15), kq = (c>>4)&3
    const int c0 = tid;
    const int a_row0 = ((c0 >> 6) << 4) + (c0 & 15);
    const int a_row1 = a_row0 + 64;          // chunk c0+256
    const int a_kq   = (c0 >> 4) & 3;

    for (int k0 = 0; k0 < K; k0 += 32) {
        {
            int rg0 = m_base + a_row0;
            int rg1 = m_base + a_row1;
            uint4 z = make_uint4(0u, 0u, 0u, 0u);
            uint4 h0 = z, l0 = z, h1 = z, l1 = z;
            if (rg0 < M) {
                h0 = *(const uint4*)(Ahi + (size_t)rg0 * K + k0 + a_kq * 8);
                l0 = *(const uint4*)(Alo + (size_t)rg0 * K + k0 + a_kq * 8);
            }
            if (rg1 < M) {
                h1 = *(const uint4*)(Ahi + (size_t)rg1 * K + k0 + a_kq * 8);
                l1 = *(const uint4*)(Alo + (size_t)rg1 * K + k0 + a_kq * 8);
            }
            AsH[c0] = h0;       AsL[c0] = l0;
            AsH[c0 + 256] = h1; AsL[c0 + 256] = l1;
            // B: 64 rows, one chunk per thread
            BsH[c0 & 255] = *(const uint4*)(Bhi + (size_t)(n_base + (a_row0 & 63)) * K + k0 + a_kq * 8);
            BsL[c0 & 255] = *(const uint4*)(Blo + (size_t)(n_base + (a_row0 & 63)) * K + k0 + a_kq * 8);
        }
        __syncthreads();

        bf16x8 aH[2], aL[2], bH[4], bL[4];
#pragma unroll
        for (int tm = 0; tm < 2; ++tm) {
            int c = (wave * 2 + tm) * 64 + lane;
            aH[tm] = *(const bf16x8*)&AsH[c];
            aL[tm] = *(const bf16x8*)&AsL[c];
        }
#pragma unroll
        for (int tn = 0; tn < 4; ++tn) {
            int c = tn * 64 + lane;
            bH[tn] = *(const bf16x8*)&BsH[c];
            bL[tn] = *(const bf16x8*)&BsL[c];
        }
#pragma unroll
        for (int tm = 0; tm < 2; ++tm)
#pragma unroll
            for (int tn = 0; tn < 4; ++tn) {
                acc[tm][tn] = __builtin_amdgcn_mfma_f32_16x16x32_bf16(aH[tm], bH[tn], acc[tm][tn], 0, 0, 0);
                acc[tm][tn] = __builtin_amdgcn_mfma_f32_16x16x32_bf16(aH[tm], bL[tn], acc[tm][tn], 0, 0, 0);
                acc[tm][tn] = __builtin_amdgcn_mfma_f32_16x16x32_bf16(aL[tm], bH[tn], acc[tm][tn], 0, 0, 0);
            }
        __syncthreads();
    }

    // epilogue: C/D layout col=lane&15, row=quad*4+i
#pragma unroll
    for (int tm = 0; tm < 2; ++tm) {
        int row0 = m_base + wave * 32 + tm * 16 + quad * 4;
#pragma unroll
        for (int i = 0; i < 4; ++i) {
            int row = row0 + i;
            if (row >= M) continue;
            float rs = ROWSCALE ? rowscale[row] : 1.0f;
#pragma unroll
            for (int tn = 0; tn < 4; ++tn) {
                int col = n_base + tn * 16 + lr;
                float v = acc[tm][tn][i];
                if (HAS_BIAS) v += bias[col];
                if (DO_TANH) v = tanhf(v);
                if (ROWSCALE) v *= rs;
                if (PAIR_OUT) {
                    u16 h = f2bf(v);
                    Chi[(size_t)row * N + col] = h;
                    Clo[(size_t)row * N + col] = f2bf(v - bf2f(h));
                } else {
                    C[(size_t)row * N + col] = v;
                }
            }
        }
    }
}

// ---------------- XCD-sliced fused gather aggregation ----------------

template<bool PRESCALED, bool HAS_BIAS, bool PAIR_OUT, int F4>
__launch_bounds__(256)
__global__ void k_gather(const float* __restrict__ h, const float* __restrict__ dinv,
                         const int* __restrict__ row_end, const int* __restrict__ csr,
                         const float* __restrict__ bias,
                         float* __restrict__ outF, u16* __restrict__ outH, u16* __restrict__ outL) {
    constexpr int NS = 8;
    constexpr int F4S = F4 / NS;
    constexpr int NPB = 256 / F4S;
    const int slice = blockIdx.x & (NS - 1);
    const int g = blockIdx.x >> 3;
    const int tid = threadIdx.x;
    const int d = g * NPB + tid / F4S;
    if (d >= NN) return;
    const int f = slice * F4S + (tid & (F4S - 1));

    const int start = (d == 0) ? 0 : row_end[d - 1];
    const int end = row_end[d];
    const float4* h4 = (const float4*)h;

    float ax = 0.f, ay = 0.f, az = 0.f, aw = 0.f;
    int e = start;
    for (; e + 8 <= end; e += 8) {
        int s[8]; float4 v[8]; float w[8];
#pragma unroll
        for (int j = 0; j < 8; ++j) s[j] = csr[e + j];
#pragma unroll
        for (int j = 0; j < 8; ++j) v[j] = h4[(size_t)s[j] * F4 + f];
#pragma unroll
        for (int j = 0; j < 8; ++j) w[j] = PRESCALED ? 1.0f : dinv[s[j]];
#pragma unroll
        for (int j = 0; j < 8; ++j) {
            ax += w[j] * v[j].x; ay += w[j] * v[j].y;
            az += w[j] * v[j].z; aw += w[j] * v[j].w;
        }
    }
    for (; e < end; ++e) {
        int s = csr[e];
        float w = PRESCALED ? 1.0f : dinv[s];
        float4 v = h4[(size_t)s * F4 + f];
        ax += w * v.x; ay += w * v.y; az += w * v.z; aw += w * v.w;
    }

    const float dd = dinv[d];
    float rx = dd * ax, ry = dd * ay, rz = dd * az, rw = dd * aw;
    if (HAS_BIAS) {
        float4 bv = ((const float4*)bias)[f];
        rx += bv.x; ry += bv.y; rz += bv.z; rw += bv.w;
    }
    if (PAIR_OUT) {
        u16 hx = f2bf(rx), hy = f2bf(ry), hz = f2bf(rz), hw = f2bf(rw);
        ushort4 vh = make_ushort4(hx, hy, hz, hw);
        ushort4 vl = make_ushort4(f2bf(rx - bf2f(hx)), f2bf(ry - bf2f(hy)),
                                  f2bf(rz - bf2f(hz)), f2bf(rw - bf2f(hw)));
        ((ushort4*)outH)[(size_t)d * F4 + f] = vh;
        ((ushort4*)outL)[(size_t)d * F4 + f] = vl;
    } else {
        ((float4*)outF)[(size_t)d * F4 + f] = make_float4(rx, ry, rz, rw);
    }
}

// ---------------- launch ----------------

extern "C" void kernel_launch(void* const* d_in, const int* in_sizes, int n_in,
                              void* d_out, int out_size, void* d_ws, size_t ws_size,
                              hipStream_t stream) {
    const float* x  = (const float*)d_in[0];
    const float* W1 = (const float*)d_in[1];
    const float* b1 = (const float*)d_in[2];
    const float* W2 = (const float*)d_in[3];
    const float* b2 = (const float*)d_in[4];
    const float* W3 = (const float*)d_in[5];
    const float* b3 = (const float*)d_in[6];
    const int* edge = (const int*)d_in[7];
    const int* src = edge;
    const int* dst = edge + NE;
    float* out = (float*)d_out;

    const size_t SLOT = (size_t)NN * HID_DIM * 4;
    char* p = (char*)d_ws;
    char* slot0 = p;
    char* slot1 = p + SLOT;
    char* q = p + 2 * SLOT;
    u16* W1Th = (u16*)q; q += (size_t)IN_DIM  * HID_DIM * 2;
    u16* W1Tl = (u16*)q; q += (size_t)IN_DIM  * HID_DIM * 2;
    u16* W2Th = (u16*)q; q += (size_t)HID_DIM * HID_DIM * 2;
    u16* W2Tl = (u16*)q; q += (size_t)HID_DIM * HID_DIM * 2;
    u16* W3Th = (u16*)q; q += (size_t)HID_DIM * OUT_DIM * 2;
    u16* W3Tl = (u16*)q; q += (size_t)HID_DIM * OUT_DIM * 2;
    int*   deg  = (int*)q;   q += (size_t)NN * 4;
    float* dinv = (float*)q; q += (size_t)NN * 4;
    int*   row  = (int*)q;   q += (size_t)NN * 4;
    int*   csr  = (int*)q;   q += (size_t)(NE + NN) * 4;

    u16* Xagg_h = (u16*)slot0;
    u16* Xagg_l = Xagg_h + (size_t)NN * IN_DIM;
    float* g1   = (float*)slot1;
    u16* H1h    = (u16*)slot0;
    u16* H1l    = H1h + (size_t)NN * HID_DIM;
    u16* h2h    = (u16*)slot1;
    u16* h2l    = h2h + (size_t)NN * HID_DIM;
    float* g3   = (float*)slot0;

    const int T = 256;
    const int MT = (NN + 127) / 128;   // 79 m-tiles
    const int MT8 = (MT + 7) / 8;      // 10

    // ---- CSR (with self loops) + dinv build ----
    k_zero_deg<<<(NN + T - 1) / T, T, 0, stream>>>(deg);
    k_count_deg<<<(NE + T - 1) / T, T, 0, stream>>>(dst, deg);
    k_scan<<<1, 1024, 0, stream>>>(deg, row, csr, dinv);
    k_fill<<<(NE + T - 1) / T, T, 0, stream>>>(src, dst, row, csr);

    {
        int total = IN_DIM * HID_DIM + HID_DIM * HID_DIM + HID_DIM * OUT_DIM;
        k_wsplit_all<<<(total + T - 1) / T, T, 0, stream>>>(W1, W2, W3, W1Th, W1Tl,
                                                            W2Th, W2Tl, W3Th, W3Tl);
    }

    const int G256 = ((NN + 31) / 32) * 8;
    const int G512 = ((NN + 15) / 16) * 8;
    const int GEMM_G512 = 8 * MT8 * (HID_DIM / 64);  // 640
    const int GEMM_G256 = 8 * MT8 * (OUT_DIM / 64);  // 320

    // ---- layer 1 ----
    k_gather<false, false, true, IN_DIM / 4><<<G256, 256, 0, stream>>>(
        x, dinv, row, csr, nullptr, nullptr, Xagg_h, Xagg_l);
    k_gemm_bf16x3<true, true, false, true><<<GEMM_G512, 256, 0, stream>>>(
        Xagg_h, Xagg_l, W1Th, W1Tl, b1, dinv, g1, nullptr, nullptr, NN, HID_DIM, IN_DIM, MT, MT8);

    // ---- layer 2 ----
    k_gather<true, false, true, HID_DIM / 4><<<G512, 256, 0, stream>>>(
        g1, dinv, row, csr, nullptr, nullptr, H1h, H1l);
    k_gemm_bf16x3<true, true, true, false><<<GEMM_G512, 256, 0, stream>>>(
        H1h, H1l, W2Th, W2Tl, b2, nullptr, nullptr, h2h, h2l, NN, HID_DIM, HID_DIM, MT, MT8);

    // ---- layer 3 ----
    k_gemm_bf16x3<false, false, false, true><<<GEMM_G256, 256, 0, stream>>>(
        h2h, h2l, W3Th, W3Tl, nullptr, dinv, g3, nullptr, nullptr, NN, OUT_DIM, HID_DIM, MT, MT8);
    k_gather<true, true, false, OUT_DIM / 4><<<G256, 256, 0, stream>>>(
        g3, dinv, row, csr, b3, out, nullptr, nullptr);

    (void)in_sizes; (void)n_in; (void)out_size; (void)ws_size;
}

// Round 7
// 258.670 us; speedup vs baseline: 1.0771x; 1.0771x over previous
//
#include <hip/hip_runtime.h>
#include <math.h>

#define NN 10000
#define NE 160000
#define IN_DIM 256
#define HID_DIM 512
#define OUT_DIM 256

typedef unsigned short u16;
typedef __attribute__((ext_vector_type(8))) short bf16x8;
typedef __attribute__((ext_vector_type(4))) float f32x4;

// ---------------- bf16 split helpers ----------------

static __device__ __forceinline__ u16 f2bf(float f) {
    union { float f; unsigned u; } v; v.f = f;
    unsigned r = v.u + 0x7fffu + ((v.u >> 16) & 1u);  // RNE
    return (u16)(r >> 16);
}
static __device__ __forceinline__ float bf2f(u16 h) {
    union { unsigned u; float f; } v; v.u = ((unsigned)h) << 16;
    return v.f;
}

// ---------------- degree / CSR build (self-loops included) ----------------

__global__ void k_zero_deg(int* __restrict__ deg) {
    int i = blockIdx.x * blockDim.x + threadIdx.x;
    if (i < NN) deg[i] = 0;
}

__global__ void k_count_deg(const int* __restrict__ dst, int* __restrict__ deg) {
    int e = blockIdx.x * blockDim.x + threadIdx.x;
    if (e < NE) atomicAdd(&deg[dst[e]], 1);
}

__launch_bounds__(1024)
__global__ void k_scan(const int* __restrict__ deg, int* __restrict__ row,
                       int* __restrict__ csr, float* __restrict__ dinv) {
    __shared__ int sdeg[10240];
    __shared__ int sums[1024];
    const int tid = threadIdx.x;
    for (int i = tid; i < NN; i += 1024) sdeg[i] = deg[i];
    __syncthreads();
    const int CH = 10;
    int base = tid * CH;
    int s = 0;
    for (int j = 0; j < CH; ++j) {
        int i = base + j;
        if (i < NN) s += sdeg[i] + 1;
    }
    sums[tid] = s;
    __syncthreads();
    for (int off = 1; off < 1024; off <<= 1) {
        int t = (tid >= off) ? sums[tid - off] : 0;
        __syncthreads();
        sums[tid] += t;
        __syncthreads();
    }
    int run = sums[tid] - s;
    for (int j = 0; j < CH; ++j) {
        int i = base + j;
        if (i < NN) {
            int dg = sdeg[i];
            csr[run] = i;
            row[i] = run + 1;
            dinv[i] = rsqrtf((float)dg + 1.0f);
            run += dg + 1;
        }
    }
}

__global__ void k_fill(const int* __restrict__ src, const int* __restrict__ dst,
                       int* __restrict__ row, int* __restrict__ csr) {
    int e = blockIdx.x * blockDim.x + threadIdx.x;
    if (e < NE) {
        int pos = atomicAdd(&row[dst[e]], 1);
        csr[pos] = src[e];
    }
}

// ---------------- fused weight transpose + bf16 hi/lo split ----------------

__global__ void k_wsplit_all(const float* __restrict__ W1, const float* __restrict__ W2,
                             const float* __restrict__ W3,
                             u16* __restrict__ W1h, u16* __restrict__ W1l,
                             u16* __restrict__ W2h, u16* __restrict__ W2l,
                             u16* __restrict__ W3h, u16* __restrict__ W3l) {
    int idx = blockIdx.x * blockDim.x + threadIdx.x;
    const int S1 = IN_DIM * HID_DIM;
    const int S2 = HID_DIM * HID_DIM;
    const int S3 = HID_DIM * OUT_DIM;
    const float* W; u16 *Th, *Tl; int K, N, local;
    if (idx < S1)           { W = W1; Th = W1h; Tl = W1l; K = IN_DIM;  N = HID_DIM; local = idx; }
    else if (idx < S1 + S2) { W = W2; Th = W2h; Tl = W2l; K = HID_DIM; N = HID_DIM; local = idx - S1; }
    else if (idx < S1 + S2 + S3) { W = W3; Th = W3h; Tl = W3l; K = HID_DIM; N = OUT_DIM; local = idx - S1 - S2; }
    else return;
    int k = local / N, n = local - k * N;
    float v = W[local];
    u16 h = f2bf(v);
    Th[(size_t)n * K + k] = h;
    Tl[(size_t)n * K + k] = f2bf(v - bf2f(h));
}

// ---------------- bf16x3 split MFMA GEMM ----------------
// XCD-pinned m-slices (id%8 -> XCD; all n-blocks of an m-tile on one XCD).
// Staging: COALESCED global pattern (lane -> row=tid>>2, kq=tid&3; 64B/4 lanes)
// written to FRAGMENT-ORDER LDS chunks c=(row>>4)*64+kq*16+(row&15) -> both
// writes and fragment reads are dense & conflict-free.
// Double-buffered LDS (48 KB), VGPR prefetch of iter k+1 issued before the
// MFMAs of iter k, ONE barrier per iter -> load latency overlapped.

template<bool HAS_BIAS, bool DO_TANH, bool PAIR_OUT, bool ROWSCALE>
__launch_bounds__(256)
__global__ void k_gemm_bf16x3(const u16* __restrict__ Ahi, const u16* __restrict__ Alo,
                              const u16* __restrict__ Bhi, const u16* __restrict__ Blo,
                              const float* __restrict__ bias, const float* __restrict__ rowscale,
                              float* __restrict__ C, u16* __restrict__ Chi, u16* __restrict__ Clo,
                              int M, int N, int K, int MT, int MT8) {
    __shared__ uint4 AsH[2][512];  // [buf][chunk]; chunk=(row>>4)*64+kq*16+(row&15)
    __shared__ uint4 AsL[2][512];
    __shared__ uint4 BsH[2][256];
    __shared__ uint4 BsL[2][256];

    const int id = blockIdx.x;
    const int xcd = id & 7;
    const int q2 = id >> 3;
    const int mt = (q2 % MT8) * 8 + xcd;
    const int nt = q2 / MT8;
    if (mt >= MT) return;

    const int tid  = threadIdx.x;
    const int wave = tid >> 6;
    const int lane = tid & 63;
    const int lr   = lane & 15;
    const int quad = lane >> 4;
    const int m_base = mt * 128;
    const int n_base = nt * 64;

    // coalesced staging assignment
    const int s_row = tid >> 2;          // 0..63
    const int s_kq  = tid & 3;           // 0..3
    const int c_lo  = ((s_row >> 4) << 6) + s_kq * 16 + (s_row & 15);  // 0..255

    const u16* pA0h = Ahi + (size_t)(m_base + s_row) * K + s_kq * 8;
    const u16* pA0l = Alo + (size_t)(m_base + s_row) * K + s_kq * 8;
    const u16* pA1h = pA0h + (size_t)64 * K;
    const u16* pA1l = pA0l + (size_t)64 * K;
    const u16* pBh  = Bhi + (size_t)(n_base + s_row) * K + s_kq * 8;
    const u16* pBl  = Blo + (size_t)(n_base + s_row) * K + s_kq * 8;
    const bool g0 = (m_base + s_row) < M;
    const bool g1 = (m_base + s_row + 64) < M;

    f32x4 acc[2][4] = {};
    const int NIT = K >> 5;
    const uint4 z = make_uint4(0u, 0u, 0u, 0u);

    // prologue: stage iter 0 into buf 0
    {
        uint4 h0 = z, l0 = z, h1 = z, l1 = z;
        if (g0) { h0 = *(const uint4*)pA0h; l0 = *(const uint4*)pA0l; }
        if (g1) { h1 = *(const uint4*)pA1h; l1 = *(const uint4*)pA1l; }
        uint4 bh = *(const uint4*)pBh;
        uint4 bl = *(const uint4*)pBl;
        AsH[0][c_lo] = h0;       AsL[0][c_lo] = l0;
        AsH[0][c_lo + 256] = h1; AsL[0][c_lo + 256] = l1;
        BsH[0][c_lo] = bh;       BsL[0][c_lo] = bl;
    }
    __syncthreads();

    for (int it = 0; it < NIT; ++it) {
        const bool has_next = (it + 1) < NIT;
        uint4 nh0 = z, nl0 = z, nh1 = z, nl1 = z, nbh = z, nbl = z;
        if (has_next) {
            const int ko = (it + 1) * 32;  // u16 elements
            if (g0) { nh0 = *(const uint4*)(pA0h + ko); nl0 = *(const uint4*)(pA0l + ko); }
            if (g1) { nh1 = *(const uint4*)(pA1h + ko); nl1 = *(const uint4*)(pA1l + ko); }
            nbh = *(const uint4*)(pBh + ko);
            nbl = *(const uint4*)(pBl + ko);
        }

        const int cur = it & 1;
        bf16x8 aH[2], aL[2], bH[4], bL[4];
#pragma unroll
        for (int tm = 0; tm < 2; ++tm) {
            int c = (wave * 2 + tm) * 64 + lane;
            aH[tm] = *(const bf16x8*)&AsH[cur][c];
            aL[tm] = *(const bf16x8*)&AsL[cur][c];
        }
#pragma unroll
        for (int tn = 0; tn < 4; ++tn) {
            int c = tn * 64 + lane;
            bH[tn] = *(const bf16x8*)&BsH[cur][c];
            bL[tn] = *(const bf16x8*)&BsL[cur][c];
        }
#pragma unroll
        for (int tm = 0; tm < 2; ++tm)
#pragma unroll
            for (int tn = 0; tn < 4; ++tn) {
                acc[tm][tn] = __builtin_amdgcn_mfma_f32_16x16x32_bf16(aH[tm], bH[tn], acc[tm][tn], 0, 0, 0);
                acc[tm][tn] = __builtin_amdgcn_mfma_f32_16x16x32_bf16(aH[tm], bL[tn], acc[tm][tn], 0, 0, 0);
                acc[tm][tn] = __builtin_amdgcn_mfma_f32_16x16x32_bf16(aL[tm], bH[tn], acc[tm][tn], 0, 0, 0);
            }

        if (has_next) {
            const int nxt = cur ^ 1;
            AsH[nxt][c_lo] = nh0;       AsL[nxt][c_lo] = nl0;
            AsH[nxt][c_lo + 256] = nh1; AsL[nxt][c_lo + 256] = nl1;
            BsH[nxt][c_lo] = nbh;       BsL[nxt][c_lo] = nbl;
        }
        __syncthreads();
    }

    // epilogue: C/D layout col=lane&15, row=quad*4+i
#pragma unroll
    for (int tm = 0; tm < 2; ++tm) {
        int row0 = m_base + wave * 32 + tm * 16 + quad * 4;
#pragma unroll
        for (int i = 0; i < 4; ++i) {
            int row = row0 + i;
            if (row >= M) continue;
            float rs = ROWSCALE ? rowscale[row] : 1.0f;
#pragma unroll
            for (int tn = 0; tn < 4; ++tn) {
                int col = n_base + tn * 16 + lr;
                float v = acc[tm][tn][i];
                if (HAS_BIAS) v += bias[col];
                if (DO_TANH) v = tanhf(v);
                if (ROWSCALE) v *= rs;
                if (PAIR_OUT) {
                    u16 h = f2bf(v);
                    Chi[(size_t)row * N + col] = h;
                    Clo[(size_t)row * N + col] = f2bf(v - bf2f(h));
                } else {
                    C[(size_t)row * N + col] = v;
                }
            }
        }
    }
}

// ---------------- XCD-sliced fused gather aggregation ----------------

template<bool PRESCALED, bool HAS_BIAS, bool PAIR_OUT, int F4>
__launch_bounds__(256)
__global__ void k_gather(const float* __restrict__ h, const float* __restrict__ dinv,
                         const int* __restrict__ row_end, const int* __restrict__ csr,
                         const float* __restrict__ bias,
                         float* __restrict__ outF, u16* __restrict__ outH, u16* __restrict__ outL) {
    constexpr int NS = 8;
    constexpr int F4S = F4 / NS;
    constexpr int NPB = 256 / F4S;
    const int slice = blockIdx.x & (NS - 1);
    const int g = blockIdx.x >> 3;
    const int tid = threadIdx.x;
    const int d = g * NPB + tid / F4S;
    if (d >= NN) return;
    const int f = slice * F4S + (tid & (F4S - 1));

    const int start = (d == 0) ? 0 : row_end[d - 1];
    const int end = row_end[d];
    const float4* h4 = (const float4*)h;

    float ax = 0.f, ay = 0.f, az = 0.f, aw = 0.f;
    int e = start;
    for (; e + 8 <= end; e += 8) {
        int s[8]; float4 v[8]; float w[8];
#pragma unroll
        for (int j = 0; j < 8; ++j) s[j] = csr[e + j];
#pragma unroll
        for (int j = 0; j < 8; ++j) v[j] = h4[(size_t)s[j] * F4 + f];
#pragma unroll
        for (int j = 0; j < 8; ++j) w[j] = PRESCALED ? 1.0f : dinv[s[j]];
#pragma unroll
        for (int j = 0; j < 8; ++j) {
            ax += w[j] * v[j].x; ay += w[j] * v[j].y;
            az += w[j] * v[j].z; aw += w[j] * v[j].w;
        }
    }
    for (; e < end; ++e) {
        int s = csr[e];
        float w = PRESCALED ? 1.0f : dinv[s];
        float4 v = h4[(size_t)s * F4 + f];
        ax += w * v.x; ay += w * v.y; az += w * v.z; aw += w * v.w;
    }

    const float dd = dinv[d];
    float rx = dd * ax, ry = dd * ay, rz = dd * az, rw = dd * aw;
    if (HAS_BIAS) {
        float4 bv = ((const float4*)bias)[f];
        rx += bv.x; ry += bv.y; rz += bv.z; rw += bv.w;
    }
    if (PAIR_OUT) {
        u16 hx = f2bf(rx), hy = f2bf(ry), hz = f2bf(rz), hw = f2bf(rw);
        ushort4 vh = make_ushort4(hx, hy, hz, hw);
        ushort4 vl = make_ushort4(f2bf(rx - bf2f(hx)), f2bf(ry - bf2f(hy)),
                                  f2bf(rz - bf2f(hz)), f2bf(rw - bf2f(hw)));
        ((ushort4*)outH)[(size_t)d * F4 + f] = vh;
        ((ushort4*)outL)[(size_t)d * F4 + f] = vl;
    } else {
        ((float4*)outF)[(size_t)d * F4 + f] = make_float4(rx, ry, rz, rw);
    }
}

// ---------------- launch ----------------

extern "C" void kernel_launch(void* const* d_in, const int* in_sizes, int n_in,
                              void* d_out, int out_size, void* d_ws, size_t ws_size,
                              hipStream_t stream) {
    const float* x  = (const float*)d_in[0];
    const float* W1 = (const float*)d_in[1];
    const float* b1 = (const float*)d_in[2];
    const float* W2 = (const float*)d_in[3];
    const float* b2 = (const float*)d_in[4];
    const float* W3 = (const float*)d_in[5];
    const float* b3 = (const float*)d_in[6];
    const int* edge = (const int*)d_in[7];
    const int* src = edge;
    const int* dst = edge + NE;
    float* out = (float*)d_out;

    const size_t SLOT = (size_t)NN * HID_DIM * 4;
    char* p = (char*)d_ws;
    char* slot0 = p;
    char* slot1 = p + SLOT;
    char* q = p + 2 * SLOT;
    u16* W1Th = (u16*)q; q += (size_t)IN_DIM  * HID_DIM * 2;
    u16* W1Tl = (u16*)q; q += (size_t)IN_DIM  * HID_DIM * 2;
    u16* W2Th = (u16*)q; q += (size_t)HID_DIM * HID_DIM * 2;
    u16* W2Tl = (u16*)q; q += (size_t)HID_DIM * HID_DIM * 2;
    u16* W3Th = (u16*)q; q += (size_t)HID_DIM * OUT_DIM * 2;
    u16* W3Tl = (u16*)q; q += (size_t)HID_DIM * OUT_DIM * 2;
    int*   deg  = (int*)q;   q += (size_t)NN * 4;
    float* dinv = (float*)q; q += (size_t)NN * 4;
    int*   row  = (int*)q;   q += (size_t)NN * 4;
    int*   csr  = (int*)q;   q += (size_t)(NE + NN) * 4;

    u16* Xagg_h = (u16*)slot0;
    u16* Xagg_l = Xagg_h + (size_t)NN * IN_DIM;
    float* g1   = (float*)slot1;
    u16* H1h    = (u16*)slot0;
    u16* H1l    = H1h + (size_t)NN * HID_DIM;
    u16* h2h    = (u16*)slot1;
    u16* h2l    = h2h + (size_t)NN * HID_DIM;
    float* g3   = (float*)slot0;

    const int T = 256;
    const int MT = (NN + 127) / 128;   // 79
    const int MT8 = (MT + 7) / 8;      // 10

    // ---- CSR (with self loops) + dinv build ----
    k_zero_deg<<<(NN + T - 1) / T, T, 0, stream>>>(deg);
    k_count_deg<<<(NE + T - 1) / T, T, 0, stream>>>(dst, deg);
    k_scan<<<1, 1024, 0, stream>>>(deg, row, csr, dinv);
    k_fill<<<(NE + T - 1) / T, T, 0, stream>>>(src, dst, row, csr);

    {
        int total = IN_DIM * HID_DIM + HID_DIM * HID_DIM + HID_DIM * OUT_DIM;
        k_wsplit_all<<<(total + T - 1) / T, T, 0, stream>>>(W1, W2, W3, W1Th, W1Tl,
                                                            W2Th, W2Tl, W3Th, W3Tl);
    }

    const int G256 = ((NN + 31) / 32) * 8;
    const int G512 = ((NN + 15) / 16) * 8;
    const int GEMM_G512 = 8 * MT8 * (HID_DIM / 64);  // 640
    const int GEMM_G256 = 8 * MT8 * (OUT_DIM / 64);  // 320

    // ---- layer 1 ----
    k_gather<false, false, true, IN_DIM / 4><<<G256, 256, 0, stream>>>(
        x, dinv, row, csr, nullptr, nullptr, Xagg_h, Xagg_l);
    k_gemm_bf16x3<true, true, false, true><<<GEMM_G512, 256, 0, stream>>>(
        Xagg_h, Xagg_l, W1Th, W1Tl, b1, dinv, g1, nullptr, nullptr, NN, HID_DIM, IN_DIM, MT, MT8);

    // ---- layer 2 ----
    k_gather<true, false, true, HID_DIM / 4><<<G512, 256, 0, stream>>>(
        g1, dinv, row, csr, nullptr, nullptr, H1h, H1l);
    k_gemm_bf16x3<true, true, true, false><<<GEMM_G512, 256, 0, stream>>>(
        H1h, H1l, W2Th, W2Tl, b2, nullptr, nullptr, h2h, h2l, NN, HID_DIM, HID_DIM, MT, MT8);

    // ---- layer 3 ----
    k_gemm_bf16x3<false, false, false, true><<<GEMM_G256, 256, 0, stream>>>(
        h2h, h2l, W3Th, W3Tl, nullptr, dinv, g3, nullptr, nullptr, NN, OUT_DIM, HID_DIM, MT, MT8);
    k_gather<true, true, false, OUT_DIM / 4><<<G256, 256, 0, stream>>>(
        g3, dinv, row, csr, b3, out, nullptr, nullptr);

    (void)in_sizes; (void)n_in; (void)out_size; (void)ws_size;
}